// Round 1
// baseline (187.383 us; speedup 1.0000x reference)
//
#include <hip/hip_runtime.h>
#include <math.h>

#define KK 5
#define Bc 5.0f
#define NN 32768
#define DD 64
#define LL 63
#define PP 14
#define MIN_Wc 0.001f
#define MIN_Hc 0.001f
#define MIN_Dc 0.001f

__device__ __forceinline__ float softplusf(float v) {
    // numerically stable log1p(exp(v)) (matches jax.nn.softplus)
    return v > 0.f ? v + log1pf(expf(-v)) : log1pf(expf(v));
}

__global__ __launch_bounds__(256) void nsf_kernel(
    const float* __restrict__ x, const float* __restrict__ init_param,
    const float* __restrict__ W1, const float* __restrict__ b1,
    const float* __restrict__ W2, const float* __restrict__ b2,
    const float* __restrict__ W3, const float* __restrict__ b3,
    float* __restrict__ out)
{
    __shared__ float xs[64 * 65];   // 64 samples x 64 dims, +1 pad (bank-conflict-free row reads)
    const int s0 = blockIdx.x * 64; // sample tile base (aligned to 64)
    const int tid = threadIdx.x;

    // stage x tile, coalesced
    for (int q = tid; q < 64 * 64; q += 256) {
        int r = q >> 6, c = q & 63;
        xs[r * 65 + c] = x[(s0 + r) * 64 + c];
    }
    __syncthreads();

    const int lane = tid & 63;
    const int wave = tid >> 6;
    const float* xrow = &xs[lane * 65];

    #pragma unroll 1
    for (int k = 0; k < 4; ++k) {
        int dd = blockIdx.y * 16 + wave * 4 + k;       // dim in [0,64)
        dd = __builtin_amdgcn_readfirstlane(dd);        // force wave-uniform -> scalar weight loads

        float p[PP];
        if (dd == 0) {
            #pragma unroll
            for (int i = 0; i < PP; ++i) p[i] = init_param[i];
        } else {
            const int l = dd - 1;
            // layer 1: h1 = tanh(sum_{j<=l} x[j]*W1[l,j,:] + b1[l,:])
            float h1[8];
            #pragma unroll
            for (int h = 0; h < 8; ++h) h1[h] = b1[l * 8 + h];
            const float* W1l = &W1[l * LL * 8];
            for (int j = 0; j <= l; ++j) {
                float xv = xrow[j];
                #pragma unroll
                for (int h = 0; h < 8; ++h) h1[h] = fmaf(xv, W1l[j * 8 + h], h1[h]);
            }
            #pragma unroll
            for (int h = 0; h < 8; ++h) h1[h] = tanhf(h1[h]);
            // layer 2: h2[g] = tanh(sum_h h1[h]*W2[l,h,g] + b2[l,g])
            float h2[8];
            const float* W2l = &W2[l * 64];
            #pragma unroll
            for (int g = 0; g < 8; ++g) h2[g] = b2[l * 8 + g];
            #pragma unroll
            for (int h = 0; h < 8; ++h) {
                #pragma unroll
                for (int g = 0; g < 8; ++g) h2[g] = fmaf(h1[h], W2l[h * 8 + g], h2[g]);
            }
            #pragma unroll
            for (int g = 0; g < 8; ++g) h2[g] = tanhf(h2[g]);
            // layer 3: p[q] = sum_g h2[g]*W3[l,g,q] + b3[l,q]
            const float* W3l = &W3[l * 8 * PP];
            #pragma unroll
            for (int q = 0; q < PP; ++q) p[q] = b3[l * PP + q];
            #pragma unroll
            for (int g = 0; g < 8; ++g) {
                #pragma unroll
                for (int q = 0; q < PP; ++q) p[q] = fmaf(h2[g], W3l[g * PP + q], p[q]);
            }
        }

        // ---- rational quadratic spline for (dim=dd, sample=s0+lane) ----
        const float xf = xrow[dd];

        // widths -> cumw
        float wmax = p[0];
        #pragma unroll
        for (int i = 1; i < KK; ++i) wmax = fmaxf(wmax, p[i]);
        float we[KK]; float wsum = 0.f;
        #pragma unroll
        for (int i = 0; i < KK; ++i) { we[i] = expf(p[i] - wmax); wsum += we[i]; }
        const float wnorm = (1.0f - MIN_Wc * KK) / wsum;
        float cumw[KK + 1], wdt[KK];
        cumw[0] = -Bc;
        float acw = 0.f;
        #pragma unroll
        for (int i = 0; i < KK; ++i) { acw += MIN_Wc + wnorm * we[i]; cumw[i + 1] = 2.f * Bc * acw - Bc; }
        cumw[KK] = Bc;
        #pragma unroll
        for (int i = 0; i < KK; ++i) wdt[i] = cumw[i + 1] - cumw[i];

        // heights -> cumh
        float hmax = p[KK];
        #pragma unroll
        for (int i = 1; i < KK; ++i) hmax = fmaxf(hmax, p[KK + i]);
        float he[KK]; float hsum = 0.f;
        #pragma unroll
        for (int i = 0; i < KK; ++i) { he[i] = expf(p[KK + i] - hmax); hsum += he[i]; }
        const float hnorm = (1.0f - MIN_Hc * KK) / hsum;
        float cumh[KK + 1], hgt[KK];
        cumh[0] = -Bc;
        float ach = 0.f;
        #pragma unroll
        for (int i = 0; i < KK; ++i) { ach += MIN_Hc + hnorm * he[i]; cumh[i + 1] = 2.f * Bc * ach - Bc; }
        cumh[KK] = Bc;
        #pragma unroll
        for (int i = 0; i < KK; ++i) hgt[i] = cumh[i + 1] - cumh[i];

        // derivatives: pad ends with softplus-inverse(1-MIN_D) -> derivs = 1.0 exactly
        float derivs[KK + 1];
        derivs[0] = 1.0f;
        derivs[KK] = 1.0f;
        #pragma unroll
        for (int i = 0; i < KK - 1; ++i) derivs[i + 1] = MIN_Dc + softplusf(p[2 * KK + i]);

        const float xc = fminf(fmaxf(xf, -Bc), Bc);

        // bin select (largest i with xc >= cumw[i], clipped to K-1)
        float icw = cumw[0], ibw = wdt[0], ich = cumh[0], ih = hgt[0];
        float idv = derivs[0], idvp1 = derivs[1];
        #pragma unroll
        for (int i = 1; i < KK; ++i) {
            bool c = xc >= cumw[i];
            icw   = c ? cumw[i]      : icw;
            ibw   = c ? wdt[i]       : ibw;
            ich   = c ? cumh[i]      : ich;
            ih    = c ? hgt[i]       : ih;
            idv   = c ? derivs[i]    : idv;
            idvp1 = c ? derivs[i + 1]: idvp1;
        }

        const float idl = ih / ibw;
        const float theta = (xc - icw) / ibw;
        const float omt = 1.0f - theta;
        const float tmt = theta * omt;
        const float num = ih * (idl * theta * theta + idv * tmt);
        const float den = idl + (idv + idvp1 - 2.0f * idl) * tmt;
        const float outv = ich + num / den;
        const float dnum = idl * idl * (idvp1 * theta * theta + 2.0f * idl * tmt + idv * omt * omt);
        const float ld = logf(dnum) - 2.0f * logf(den);

        const bool inside = (xf >= -Bc) && (xf <= Bc);
        const float z = inside ? outv : xf;
        float ldv = inside ? ld : 0.0f;

        out[dd * NN + s0 + lane] = z;   // coalesced

        // out1[i] = sum of lds over flat [i*64, i*64+64) == this wave exactly
        #pragma unroll
        for (int off = 32; off > 0; off >>= 1) ldv += __shfl_down(ldv, off);
        if (lane == 0) out[NN * DD + dd * (NN / 64) + blockIdx.x] = ldv;
    }
}

extern "C" void kernel_launch(void* const* d_in, const int* in_sizes, int n_in,
                              void* d_out, int out_size, void* d_ws, size_t ws_size,
                              hipStream_t stream) {
    const float* x          = (const float*)d_in[0];
    const float* init_param = (const float*)d_in[1];
    const float* W1         = (const float*)d_in[2];
    const float* b1         = (const float*)d_in[3];
    const float* W2         = (const float*)d_in[4];
    const float* b2         = (const float*)d_in[5];
    const float* W3         = (const float*)d_in[6];
    const float* b3         = (const float*)d_in[7];
    float* out = (float*)d_out;

    dim3 grid(NN / 64, 4);  // 512 sample tiles x 4 dim-groups of 16
    nsf_kernel<<<grid, 256, 0, stream>>>(x, init_param, W1, b1, W2, b2, W3, b3, out);
}

// Round 2
// 118.820 us; speedup vs baseline: 1.5770x; 1.5770x over previous
//
#include <hip/hip_runtime.h>
#include <math.h>

#define KK 5
#define Bc 5.0f
#define NN 32768
#define DD 64
#define LL 63
#define PP 14
#define MIN_Wc 0.001f
#define MIN_Hc 0.001f
#define MIN_Dc 0.001f

__device__ __forceinline__ float rcp_fast(float v) {
    return __builtin_amdgcn_rcpf(v);          // v_rcp_f32, ~1 ulp(22bit)
}
__device__ __forceinline__ float exp_fast(float v) {
    return __expf(v);                          // v_exp_f32 path
}
__device__ __forceinline__ float log_fast(float v) {
    return __logf(v);                          // v_log_f32 path
}
__device__ __forceinline__ float tanh_fast(float v) {
    // tanh(x) = 1 - 2/(exp(2x)+1); exp overflow -> inf -> rcp -> 0 -> 1 (correct)
    float e = exp_fast(2.0f * v);
    return 1.0f - 2.0f * rcp_fast(e + 1.0f);
}
__device__ __forceinline__ float softplus_fast(float v) {
    // log(1+e^v); for large v e^v==inf would give inf, so branch (wave-coherent-ish, cheap)
    return (v > 15.0f) ? v : log_fast(1.0f + exp_fast(v));
}

__global__ __launch_bounds__(256) void nsf_kernel(
    const float* __restrict__ x, const float* __restrict__ init_param,
    const float* __restrict__ W1, const float* __restrict__ b1,
    const float* __restrict__ W2, const float* __restrict__ b2,
    const float* __restrict__ W3, const float* __restrict__ b3,
    float* __restrict__ out)
{
    __shared__ float xs[64 * 65];   // 64 samples x 64 dims, +1 pad (conflict-free row reads)
    const int s0 = blockIdx.x * 64; // sample tile base
    const int tid = threadIdx.x;

    for (int q = tid; q < 64 * 64; q += 256) {
        int r = q >> 6, c = q & 63;
        xs[r * 65 + c] = x[(s0 + r) * 64 + c];
    }
    __syncthreads();

    const int lane = tid & 63;
    const int wave = tid >> 6;
    const float* xrow = &xs[lane * 65];
    const int t = blockIdx.y * 4 + wave;     // 0..15, wave-uniform

    #pragma unroll 1
    for (int k = 0; k < 4; ++k) {
        // balanced dim set {t, 31-t, 32+t, 63-t}: layer-1 trip counts sum to 126 per wave
        int dd;
        switch (k) {
            case 0: dd = t;       break;
            case 1: dd = 31 - t;  break;
            case 2: dd = 32 + t;  break;
            default: dd = 63 - t; break;
        }
        dd = __builtin_amdgcn_readfirstlane(dd);  // wave-uniform -> scalar weight loads

        float p[PP];
        if (dd == 0) {
            #pragma unroll
            for (int i = 0; i < PP; ++i) p[i] = init_param[i];
        } else {
            const int l = dd - 1;
            float h1[8];
            #pragma unroll
            for (int h = 0; h < 8; ++h) h1[h] = b1[l * 8 + h];
            const float* W1l = &W1[l * LL * 8];
            for (int j = 0; j <= l; ++j) {
                float xv = xrow[j];
                #pragma unroll
                for (int h = 0; h < 8; ++h) h1[h] = fmaf(xv, W1l[j * 8 + h], h1[h]);
            }
            #pragma unroll
            for (int h = 0; h < 8; ++h) h1[h] = tanh_fast(h1[h]);

            float h2[8];
            const float* W2l = &W2[l * 64];
            #pragma unroll
            for (int g = 0; g < 8; ++g) h2[g] = b2[l * 8 + g];
            #pragma unroll
            for (int h = 0; h < 8; ++h) {
                #pragma unroll
                for (int g = 0; g < 8; ++g) h2[g] = fmaf(h1[h], W2l[h * 8 + g], h2[g]);
            }
            #pragma unroll
            for (int g = 0; g < 8; ++g) h2[g] = tanh_fast(h2[g]);

            const float* W3l = &W3[l * 8 * PP];
            #pragma unroll
            for (int q = 0; q < PP; ++q) p[q] = b3[l * PP + q];
            #pragma unroll
            for (int g = 0; g < 8; ++g) {
                #pragma unroll
                for (int q = 0; q < PP; ++q) p[q] = fmaf(h2[g], W3l[g * PP + q], p[q]);
            }
        }

        // ---- rational quadratic spline ----
        const float xf = xrow[dd];

        float wmax = p[0];
        #pragma unroll
        for (int i = 1; i < KK; ++i) wmax = fmaxf(wmax, p[i]);
        float we[KK]; float wsum = 0.f;
        #pragma unroll
        for (int i = 0; i < KK; ++i) { we[i] = exp_fast(p[i] - wmax); wsum += we[i]; }
        const float wnorm = (1.0f - MIN_Wc * KK) * rcp_fast(wsum);
        float cumw[KK + 1], wdt[KK];
        cumw[0] = -Bc;
        float acw = 0.f;
        #pragma unroll
        for (int i = 0; i < KK; ++i) { acw += MIN_Wc + wnorm * we[i]; cumw[i + 1] = 2.f * Bc * acw - Bc; }
        cumw[KK] = Bc;
        #pragma unroll
        for (int i = 0; i < KK; ++i) wdt[i] = cumw[i + 1] - cumw[i];

        float hmax = p[KK];
        #pragma unroll
        for (int i = 1; i < KK; ++i) hmax = fmaxf(hmax, p[KK + i]);
        float he[KK]; float hsum = 0.f;
        #pragma unroll
        for (int i = 0; i < KK; ++i) { he[i] = exp_fast(p[KK + i] - hmax); hsum += he[i]; }
        const float hnorm = (1.0f - MIN_Hc * KK) * rcp_fast(hsum);
        float cumh[KK + 1], hgt[KK];
        cumh[0] = -Bc;
        float ach = 0.f;
        #pragma unroll
        for (int i = 0; i < KK; ++i) { ach += MIN_Hc + hnorm * he[i]; cumh[i + 1] = 2.f * Bc * ach - Bc; }
        cumh[KK] = Bc;
        #pragma unroll
        for (int i = 0; i < KK; ++i) hgt[i] = cumh[i + 1] - cumh[i];

        float derivs[KK + 1];
        derivs[0] = 1.0f;
        derivs[KK] = 1.0f;
        #pragma unroll
        for (int i = 0; i < KK - 1; ++i) derivs[i + 1] = MIN_Dc + softplus_fast(p[2 * KK + i]);

        const float xc = fminf(fmaxf(xf, -Bc), Bc);

        float icw = cumw[0], ibw = wdt[0], ich = cumh[0], ih = hgt[0];
        float idv = derivs[0], idvp1 = derivs[1];
        #pragma unroll
        for (int i = 1; i < KK; ++i) {
            bool c = xc >= cumw[i];
            icw   = c ? cumw[i]      : icw;
            ibw   = c ? wdt[i]       : ibw;
            ich   = c ? cumh[i]      : ich;
            ih    = c ? hgt[i]       : ih;
            idv   = c ? derivs[i]    : idv;
            idvp1 = c ? derivs[i + 1]: idvp1;
        }

        const float ibw_r = rcp_fast(ibw);
        const float idl = ih * ibw_r;
        const float theta = (xc - icw) * ibw_r;
        const float omt = 1.0f - theta;
        const float tmt = theta * omt;
        const float num = ih * (idl * theta * theta + idv * tmt);
        const float den = idl + (idv + idvp1 - 2.0f * idl) * tmt;
        const float outv = ich + num * rcp_fast(den);
        const float dnum = idl * idl * (idvp1 * theta * theta + 2.0f * idl * tmt + idv * omt * omt);
        const float ld = log_fast(dnum) - 2.0f * log_fast(den);

        const bool inside = (xf >= -Bc) && (xf <= Bc);
        const float z = inside ? outv : xf;
        float ldv = inside ? ld : 0.0f;

        out[dd * NN + s0 + lane] = z;   // coalesced

        #pragma unroll
        for (int off = 32; off > 0; off >>= 1) ldv += __shfl_down(ldv, off);
        if (lane == 0) out[NN * DD + dd * (NN / 64) + blockIdx.x] = ldv;
    }
}

extern "C" void kernel_launch(void* const* d_in, const int* in_sizes, int n_in,
                              void* d_out, int out_size, void* d_ws, size_t ws_size,
                              hipStream_t stream) {
    const float* x          = (const float*)d_in[0];
    const float* init_param = (const float*)d_in[1];
    const float* W1         = (const float*)d_in[2];
    const float* b1         = (const float*)d_in[3];
    const float* W2         = (const float*)d_in[4];
    const float* b2         = (const float*)d_in[5];
    const float* W3         = (const float*)d_in[6];
    const float* b3         = (const float*)d_in[7];
    float* out = (float*)d_out;

    dim3 grid(NN / 64, 4);  // 512 sample tiles x 4 dim-groups
    nsf_kernel<<<grid, 256, 0, stream>>>(x, init_param, W1, b1, W2, b2, W3, b3, out);
}